// Round 4
// baseline (1007.651 us; speedup 1.0000x reference)
//
#include <hip/hip_runtime.h>
#include <hip/hip_bf16.h>
#include <math.h>

typedef __attribute__((ext_vector_type(8))) short short8;   // 8 x bf16 (4 VGPRs)
typedef __attribute__((ext_vector_type(4))) float floatx4;  // MFMA C/D frag

static __device__ __forceinline__ unsigned short f2bf(float f) {
    unsigned int u = __float_as_uint(f);
    unsigned int r = (u + 0x7fffu + ((u >> 16) & 1u)) >> 16;   // RNE
    return (unsigned short)r;
}
static __device__ __forceinline__ float bf2f(unsigned short h) {
    return __uint_as_float(((unsigned int)h) << 16);
}

// ---------------------------------------------------------------------------
// Grouped bf16 MFMA GEMM with register-staged, distance-2 software pipeline.
//   C[M,N] = A[M,K] @ W[N,K]^T
// Staging: global_load_dwordx4 -> VGPR -> ds_write_b128 (NOT global_load_lds:
// plain loads stay in flight across __syncthreads; only lgkmcnt drains).
// A fp32 (converted in regs, zero-pad via Kreal) or bf16. W bf16.
// Tiles 128x128, BK=32, 4 waves x (4x4) mfma_f32_16x16x32_bf16.
// ---------------------------------------------------------------------------
struct GDesc {
    const float*          Af;    // fp32 A (or null)
    const unsigned short* Ab;    // bf16 A (or null)
    const unsigned short* W;     // bf16 W, row stride K
    float*          Cf;          // fp32 out (or null)
    unsigned short* Cb;          // bf16 out (or null)
    const float *bias, *g, *b, *m, *v;
    int M, N, K;                 // K padded to mult of 32
    int Kreal;                   // A row stride / true K
    int fuse;                    // BN+ReLU epilogue
    int nbx;                     // N/128
    int block0;                  // first flat block of group
    int swz;                     // 1: XCD-locality swizzle (needs nby%8==0, nbx==4)
};
struct GArgs { GDesc g[3]; int n; };

__global__ __launch_bounds__(256)
void gemm_pipe(GArgs ga)
{
    __shared__ unsigned short As[2][4096];   // 128 rows x 32 k
    __shared__ unsigned short Bs[2][4096];

    const int bid = blockIdx.x;
    int gi = 0;
    #pragma unroll
    for (int i = 1; i < 3; ++i)
        if (i < ga.n && bid >= ga.g[i].block0) gi = i;
    const GDesc d = ga.g[gi];
    const int local = bid - d.block0;
    int bx, by;
    if (d.swz) {               // 4 col-blocks of a row-strip -> same XCD (bid%8)
        const int xcd = local & 7, t = local >> 3;
        bx = t & 3;
        by = (t >> 2) * 8 + xcd;
    } else {
        bx = local % d.nbx;
        by = local / d.nbx;
    }
    const int row0 = by * 128;
    const int col0 = bx * 128;

    const int tid  = threadIdx.x;
    const int wave = tid >> 6;
    const int lane = tid & 63;
    const int qd   = lane >> 4;
    const int ln   = lane & 15;
    const int wr   = (wave >> 1) * 64;
    const int wc   = (wave & 1) * 64;

    // staging: chunk c covers (row=c>>2, koff=(c&3)*8); thread owns c=tid, tid+256
    const int r0  = tid >> 2;          // 0..63
    const int ko0 = (tid & 3) * 8;
    const int r1  = r0 + 64;

    const bool afp = (d.Af != nullptr);
    const int T = d.K >> 5;

    float4 fa[2][4];    // fp32 A stage: [set][chunk*2 + half]
    uint4  ba[2][2];    // bf16 A stage
    uint4  bb[2][2];    // W stage

    auto LOAD = [&](int s, int kk) {
        if (afp) {
            if (kk + ko0 < d.Kreal) {   // Kreal%8==0 -> chunk-granular pad
                const float* p0 = d.Af + (size_t)(row0 + r0) * d.Kreal + kk + ko0;
                fa[s][0] = *(const float4*)p0;
                fa[s][1] = *(const float4*)(p0 + 4);
            } else {
                fa[s][0] = fa[s][1] = (float4){0.f, 0.f, 0.f, 0.f};
            }
            if (kk + ko0 < d.Kreal) {
                const float* p1 = d.Af + (size_t)(row0 + r1) * d.Kreal + kk + ko0;
                fa[s][2] = *(const float4*)p1;
                fa[s][3] = *(const float4*)(p1 + 4);
            } else {
                fa[s][2] = fa[s][3] = (float4){0.f, 0.f, 0.f, 0.f};
            }
        } else {
            ba[s][0] = *(const uint4*)(d.Ab + (size_t)(row0 + r0) * d.K + kk + ko0);
            ba[s][1] = *(const uint4*)(d.Ab + (size_t)(row0 + r1) * d.K + kk + ko0);
        }
        bb[s][0] = *(const uint4*)(d.W + (size_t)(col0 + r0) * d.K + kk + ko0);
        bb[s][1] = *(const uint4*)(d.W + (size_t)(col0 + r1) * d.K + kk + ko0);
    };
    auto PACK = [&](const float4& lo, const float4& hi) -> uint4 {
        uint4 pk;
        pk.x = f2bf(lo.x) | ((unsigned)f2bf(lo.y) << 16);
        pk.y = f2bf(lo.z) | ((unsigned)f2bf(lo.w) << 16);
        pk.z = f2bf(hi.x) | ((unsigned)f2bf(hi.y) << 16);
        pk.w = f2bf(hi.z) | ((unsigned)f2bf(hi.w) << 16);
        return pk;
    };
    auto STORE = [&](int s, int buf) {
        if (afp) {
            *(uint4*)&As[buf][tid * 8]        = PACK(fa[s][0], fa[s][1]);
            *(uint4*)&As[buf][tid * 8 + 2048] = PACK(fa[s][2], fa[s][3]);
        } else {
            *(uint4*)&As[buf][tid * 8]        = ba[s][0];
            *(uint4*)&As[buf][tid * 8 + 2048] = ba[s][1];
        }
        *(uint4*)&Bs[buf][tid * 8]        = bb[s][0];
        *(uint4*)&Bs[buf][tid * 8 + 2048] = bb[s][1];
    };

    floatx4 acc[4][4];
    #pragma unroll
    for (int i = 0; i < 4; ++i)
        #pragma unroll
        for (int j = 0; j < 4; ++j) acc[i][j] = (floatx4){0.f, 0.f, 0.f, 0.f};

    // prologue: tiles 0,1 into reg sets; tile 0 into LDS buf 0
    LOAD(0, 0);
    if (T > 1) LOAD(1, 32);
    STORE(0, 0);
    __syncthreads();

    int cur = 0;
    for (int it = 0; it < T; ++it) {
        if (it + 2 < T) LOAD(it & 1, (it + 2) * 32);   // loads stay in flight

        short8 a[4], b[4];
        #pragma unroll
        for (int i = 0; i < 4; ++i)
            a[i] = *(const short8*)&As[cur][(wr + i * 16 + ln) * 32 + qd * 8];
        #pragma unroll
        for (int j = 0; j < 4; ++j)
            b[j] = *(const short8*)&Bs[cur][(wc + j * 16 + ln) * 32 + qd * 8];
        #pragma unroll
        for (int i = 0; i < 4; ++i)
            #pragma unroll
            for (int j = 0; j < 4; ++j)
                acc[i][j] = __builtin_amdgcn_mfma_f32_16x16x32_bf16(
                                a[i], b[j], acc[i][j], 0, 0, 0);

        if (it + 1 < T) STORE((it + 1) & 1, cur ^ 1);  // waits only its own vmcnt
        __syncthreads();
        cur ^= 1;
    }

    // epilogue: C/D layout col = lane&15, row = quad*4 + reg
    #pragma unroll
    for (int j = 0; j < 4; ++j) {
        const int col = col0 + wc + j * 16 + ln;
        float add = d.bias ? d.bias[col] : 0.f;
        float scale = 1.f, shift = 0.f;
        if (d.fuse) {
            scale = d.g[col] * rsqrtf(d.v[col] + 1e-5f);
            shift = d.b[col] - d.m[col] * scale;
        }
        #pragma unroll
        for (int i = 0; i < 4; ++i) {
            #pragma unroll
            for (int r = 0; r < 4; ++r) {
                const int row = row0 + wr + i * 16 + qd * 4 + r;
                float vv = acc[i][j][r] + add;
                if (d.fuse) vv = fmaxf(vv * scale + shift, 0.f);
                if (d.Cf) d.Cf[(size_t)row * d.N + col] = vv;
                if (d.Cb) d.Cb[(size_t)row * d.N + col] = f2bf(vv);
            }
        }
    }
}

// ---------------------------------------------------------------------------
// One-shot weight conversion fp32 -> bf16 (fc weight zero-padded 688->704)
// ---------------------------------------------------------------------------
struct WSeg { const float* src; unsigned short* dst; int Kreal; int Kp; };
struct WArgs { WSeg s[7]; int off[8]; };

__global__ __launch_bounds__(256)
void cvt_weights(WArgs wa)
{
    int i = blockIdx.x * 256 + threadIdx.x;
    if (i >= wa.off[7]) return;
    int s = 0;
    #pragma unroll
    for (int j = 1; j < 7; ++j) if (i >= wa.off[j]) s = j;
    const WSeg sg = wa.s[s];
    const int li = i - wa.off[s];
    const int r = li / sg.Kp, c = li - r * sg.Kp;
    sg.dst[li] = (c < sg.Kreal) ? f2bf(sg.src[(size_t)r * sg.Kreal + c])
                                : (unsigned short)0;
}

// ---------------------------------------------------------------------------
// Fused attention per batch row. MLP outputs now bf16.
// ---------------------------------------------------------------------------
__global__ __launch_bounds__(256)
void attn_kernel(const unsigned short* __restrict__ obj,
                 const float* __restrict__ bbox,
                 const float* __restrict__ word,
                 const unsigned short* __restrict__ sen,
                 const unsigned short* __restrict__ bod,
                 const float* __restrict__ Wc1, const float* __restrict__ Wc2,
                 const float* __restrict__ Wsa,
                 float* __restrict__ xsum_out)
{
    const int b = blockIdx.x;
    const int tid = threadIdx.x;
    const int wave = tid >> 6;
    const int lane = tid & 63;

    __shared__ float xs[10][688];
    __shared__ float s0[688], s1[688];
    __shared__ float avec[10], mvec[10], att[10];
    __shared__ float cw[14], c1[50], c2[50];

    if (tid < 14) cw[tid] = Wsa[tid];
    if (tid < 50) { c1[tid] = Wc1[tid]; c2[tid] = Wc2[tid]; }

    for (int n = 0; n < 10; ++n) {
        const unsigned short* o = obj + ((size_t)b * 10 + n) * 128;
        const float* bx = bbox + ((size_t)b * 10 + n) * 4;
        const float* w  = word + ((size_t)b * 10 + n) * 300;
        const unsigned short* s = sen + ((size_t)b * 10 + n) * 128;
        const unsigned short* bo = bod + (size_t)b * 128;
        for (int c = tid; c < 688; c += 256) {
            float v;
            if      (c < 128) v = bf2f(o[c]);
            else if (c < 132) v = bx[c - 128];
            else if (c < 432) v = w[c - 132];
            else if (c < 560) v = bf2f(s[c - 432]);
            else              v = bf2f(bo[c - 560]);
            xs[n][c] = v;
        }
    }
    __syncthreads();

    // channel stats: wave-parallel (wave w handles rows w, w+4, w+8)
    for (int n = wave; n < 10; n += 4) {
        float sm = 0.f, mx = -INFINITY;
        for (int c = lane; c < 688; c += 64) {
            float v = xs[n][c];
            sm += v; mx = fmaxf(mx, v);
        }
        #pragma unroll
        for (int off = 32; off > 0; off >>= 1) {
            sm += __shfl_down(sm, off);
            mx = fmaxf(mx, __shfl_down(mx, off));
        }
        if (lane == 0) { avec[n] = sm * (1.f / 688.f); mvec[n] = mx; }
    }
    __syncthreads();

    if (tid == 0) {
        float ha[5], hm[5];
        #pragma unroll
        for (int i = 0; i < 5; ++i) {
            float sa_ = 0.f, sm_ = 0.f;
            #pragma unroll
            for (int j = 0; j < 10; ++j) {
                sa_ += c1[i * 10 + j] * avec[j];
                sm_ += c1[i * 10 + j] * mvec[j];
            }
            ha[i] = fmaxf(sa_, 0.f);
            hm[i] = fmaxf(sm_, 0.f);
        }
        #pragma unroll
        for (int j = 0; j < 10; ++j) {
            float v = 0.f;
            #pragma unroll
            for (int i = 0; i < 5; ++i) v += c2[j * 5 + i] * (ha[i] + hm[i]);
            att[j] = 1.f / (1.f + expf(-v));
        }
    }
    __syncthreads();

    for (int c = tid; c < 688; c += 256) {
        float sm = 0.f, mx = -INFINITY;
        #pragma unroll
        for (int n = 0; n < 10; ++n) {
            float v = xs[n][c] * att[n];
            xs[n][c] = v;
            sm += v; mx = fmaxf(mx, v);
        }
        s0[c] = sm * 0.1f;
        s1[c] = mx;
    }
    __syncthreads();

    for (int c = tid; c < 688; c += 256) {
        float sa = 0.f;
        #pragma unroll
        for (int j = 0; j < 7; ++j) {
            int cc = c + j - 3;
            if (cc >= 0 && cc < 688)
                sa += cw[j] * s0[cc] + cw[7 + j] * s1[cc];
        }
        float sig = 1.f / (1.f + expf(-sa));
        float sm = 0.f;
        #pragma unroll
        for (int n = 0; n < 10; ++n) sm += xs[n][c];
        xsum_out[(size_t)b * 688 + c] = sm * sig;
    }
}

// ---------------------------------------------------------------------------
extern "C" void kernel_launch(void* const* d_in, const int* in_sizes, int n_in,
                              void* d_out, int out_size, void* d_ws, size_t ws_size,
                              hipStream_t stream)
{
    const float* f_obj = (const float*)d_in[0];
    const float* bbox  = (const float*)d_in[1];
    const float* word  = (const float*)d_in[2];
    const float* sent  = (const float*)d_in[3];
    const float* body  = (const float*)d_in[4];
    const float* W1_o  = (const float*)d_in[5];
    const float* g_o = (const float*)d_in[6],  *b_o = (const float*)d_in[7];
    const float* m_o = (const float*)d_in[8],  *v_o = (const float*)d_in[9];
    const float* W2_o  = (const float*)d_in[10];
    const float* W1_s  = (const float*)d_in[11];
    const float* g_s = (const float*)d_in[12], *b_s = (const float*)d_in[13];
    const float* m_s = (const float*)d_in[14], *v_s = (const float*)d_in[15];
    const float* W2_s  = (const float*)d_in[16];
    const float* W1_b  = (const float*)d_in[17];
    const float* g_b = (const float*)d_in[18], *b_b = (const float*)d_in[19];
    const float* m_b = (const float*)d_in[20], *v_b = (const float*)d_in[21];
    const float* W2_b  = (const float*)d_in[22];
    const float* Wc1 = (const float*)d_in[23];
    const float* Wc2 = (const float*)d_in[24];
    const float* Wsa = (const float*)d_in[25];
    const float* Wf  = (const float*)d_in[26];
    const float* bf  = (const float*)d_in[27];
    const float* g_f = (const float*)d_in[28], *b_f = (const float*)d_in[29];
    const float* m_f = (const float*)d_in[30], *v_f = (const float*)d_in[31];
    float* out = (float*)d_out;

    // ---- workspace carve; total ~28.0 MB (small ws = less harness poison) ----
    char* p = (char*)d_ws;
    unsigned short* w1s = (unsigned short*)p; p += 4194304;   // 512*4096
    unsigned short* w2s = (unsigned short*)p; p += 131072;    // 128*512
    unsigned short* w1o = (unsigned short*)p; p += 262144;    // 128*1024
    unsigned short* w2o = (unsigned short*)p; p += 32768;     // 128*128
    unsigned short* w1b = (unsigned short*)p; p += 1048576;   // 256*2048
    unsigned short* w2b = (unsigned short*)p; p += 65536;     // 128*256
    unsigned short* wfp = (unsigned short*)p; p += 360448;    // 256*704 padded
    unsigned short* h_s = (unsigned short*)p; p += 10485760;  // 10240*512
    unsigned short* h_o = (unsigned short*)p; p += 2621440;   // 10240*128
    unsigned short* h_b = (unsigned short*)p; p += 524288;    // 1024*256
    unsigned short* sen_b = (unsigned short*)p; p += 2621440; // 10240*128
    unsigned short* obj_b = (unsigned short*)p; p += 2621440; // 10240*128
    unsigned short* bod_b = (unsigned short*)p; p += 262144;  // 1024*128
    float* xsum_f = (float*)p; p += 2818048;                  // 1024*688
    if ((size_t)(p - (char*)d_ws) > ws_size) return;

    // ---- 1) weights -> bf16 ----
    WArgs wa;
    wa.s[0] = { W1_s, w1s, 4096, 4096 };
    wa.s[1] = { W2_s, w2s,  512,  512 };
    wa.s[2] = { W1_o, w1o, 1024, 1024 };
    wa.s[3] = { W2_o, w2o,  128,  128 };
    wa.s[4] = { W1_b, w1b, 2048, 2048 };
    wa.s[5] = { W2_b, w2b,  256,  256 };
    wa.s[6] = { Wf,   wfp,  688,  704 };
    const int wn[7] = { 512*4096, 128*512, 128*1024, 128*128, 256*2048, 128*256, 256*704 };
    wa.off[0] = 0;
    for (int i = 0; i < 7; ++i) wa.off[i + 1] = wa.off[i] + wn[i];
    cvt_weights<<<(wa.off[7] + 255) / 256, 256, 0, stream>>>(wa);

    // ---- 2) stage-1 grouped GEMM (fp32 A fused-convert; BN+ReLU; bf16 out) ----
    {
        GArgs ga; ga.n = 3;
        ga.g[0] = { sent,  nullptr, w1s, nullptr, h_s, nullptr, g_s, b_s, m_s, v_s,
                    10240, 512, 4096, 4096, 1, 4, 0, 1 };      // swizzled
        ga.g[1] = { f_obj, nullptr, w1o, nullptr, h_o, nullptr, g_o, b_o, m_o, v_o,
                    10240, 128, 1024, 1024, 1, 1, 320, 0 };
        ga.g[2] = { body,  nullptr, w1b, nullptr, h_b, nullptr, g_b, b_b, m_b, v_b,
                    1024, 256, 2048, 2048, 1, 2, 400, 0 };
        gemm_pipe<<<416, 256, 0, stream>>>(ga);
    }

    // ---- 3) stage-2 grouped GEMM (bf16 A; bf16 out) ----
    {
        GArgs ga; ga.n = 3;
        ga.g[0] = { nullptr, h_s, w2s, nullptr, sen_b, nullptr, nullptr, nullptr, nullptr, nullptr,
                    10240, 128, 512, 512, 0, 1, 0, 0 };
        ga.g[1] = { nullptr, h_o, w2o, nullptr, obj_b, nullptr, nullptr, nullptr, nullptr, nullptr,
                    10240, 128, 128, 128, 0, 1, 80, 0 };
        ga.g[2] = { nullptr, h_b, w2b, nullptr, bod_b, nullptr, nullptr, nullptr, nullptr, nullptr,
                    1024, 128, 256, 256, 0, 1, 160, 0 };
        gemm_pipe<<<168, 256, 0, stream>>>(ga);
    }

    // ---- 4) fused attention + sum over N ----
    attn_kernel<<<1024, 256, 0, stream>>>(obj_b, bbox, word, sen_b, bod_b,
                                          Wc1, Wc2, Wsa, xsum_f);

    // ---- 5) fc1 (+bias, BN, ReLU), K 688 zero-padded to 704 in staging ----
    {
        GArgs ga; ga.n = 1;
        ga.g[0] = { xsum_f, nullptr, wfp, out, nullptr, bf, g_f, b_f, m_f, v_f,
                    1024, 256, 704, 688, 1, 2, 0, 0 };
        gemm_pipe<<<16, 256, 0, stream>>>(ga);
    }
}

// Round 5
// 641.616 us; speedup vs baseline: 1.5705x; 1.5705x over previous
//
#include <hip/hip_runtime.h>
#include <hip/hip_bf16.h>
#include <math.h>

typedef __attribute__((ext_vector_type(8))) short short8;   // 8 x bf16 (4 VGPRs)
typedef __attribute__((ext_vector_type(4))) float floatx4;  // MFMA C/D frag

static __device__ __forceinline__ unsigned short f2bf(float f) {
    unsigned int u = __float_as_uint(f);
    unsigned int r = (u + 0x7fffu + ((u >> 16) & 1u)) >> 16;   // RNE
    return (unsigned short)r;
}
static __device__ __forceinline__ float bf2f(unsigned short h) {
    return __uint_as_float(((unsigned int)h) << 16);
}

// ---------------------------------------------------------------------------
// Grouped bf16 MFMA GEMM, register-staged distance-2 software pipeline.
//   C[M,N] = A[M,K] @ W[N,K]^T
// Staging: global_load_dwordx4 -> VGPR -> ds_write_b128. Plain loads stay in
// flight across __syncthreads (only lgkmcnt + own vmcnt drain at ds_write).
// CRITICAL: all staging-set indices are compile-time literals (round-4 used
// runtime `it&1` -> arrays demoted to scratch -> 770MB HBM write traffic).
// Requires T = K/32 EVEN (true for all GEMMs here: 128,32,64,16,4,8,22).
// ---------------------------------------------------------------------------
struct GDesc {
    const float*          Af;    // fp32 A (or null)
    const unsigned short* Ab;    // bf16 A (or null)
    const unsigned short* W;     // bf16 W, row stride K
    float*          Cf;          // fp32 out (or null)
    unsigned short* Cb;          // bf16 out (or null)
    const float *bias, *g, *b, *m, *v;
    int M, N, K;                 // K padded to mult of 32
    int Kreal;                   // A row stride / true K (chunk-granular pad, %8==0)
    int fuse;                    // BN+ReLU epilogue
    int nbx;                     // N/128
    int block0;                  // first flat block of group
    int swz;                     // 1: XCD swizzle (needs nby%8==0, nbx==4)
};
struct GArgs { GDesc g[3]; int n; };

__global__ __launch_bounds__(256)
void gemm_pipe(GArgs ga)
{
    __shared__ unsigned short As[2][4096];   // 128 rows x 32 k
    __shared__ unsigned short Bs[2][4096];

    const int bid = blockIdx.x;
    int gi = 0;
    #pragma unroll
    for (int i = 1; i < 3; ++i)
        if (i < ga.n && bid >= ga.g[i].block0) gi = i;
    const GDesc d = ga.g[gi];
    const int local = bid - d.block0;
    int bx, by;
    if (d.swz) {               // 4 col-blocks of a row-strip -> same XCD (bid%8)
        const int xcd = local & 7, t = local >> 3;
        bx = t & 3;
        by = (t >> 2) * 8 + xcd;
    } else {
        bx = local % d.nbx;
        by = local / d.nbx;
    }
    const int row0 = by * 128;
    const int col0 = bx * 128;

    const int tid  = threadIdx.x;
    const int wave = tid >> 6;
    const int lane = tid & 63;
    const int qd   = lane >> 4;
    const int ln   = lane & 15;
    const int wr   = (wave >> 1) * 64;
    const int wc   = (wave & 1) * 64;

    // staging: chunk c covers (row=c>>2, koff=(c&3)*8); thread owns c=tid, tid+256
    const int r0  = tid >> 2;          // 0..63
    const int ko0 = (tid & 3) * 8;
    const int r1  = r0 + 64;

    const bool afp = (d.Af != nullptr);
    const int T = d.K >> 5;

    // two STATIC staging sets (never runtime-indexed!)
    float4 fa0[4], fa1[4];
    uint4  ba0[2], ba1[2];
    uint4  bb0[2], bb1[2];

#define LOAD(S, kk)                                                            \
    do {                                                                       \
        if (afp) {                                                             \
            if ((kk) + ko0 < d.Kreal) {                                        \
                const float* p0_ = d.Af + (size_t)(row0 + r0) * d.Kreal + (kk) + ko0; \
                fa##S[0] = *(const float4*)p0_;                                \
                fa##S[1] = *(const float4*)(p0_ + 4);                          \
                const float* p1_ = d.Af + (size_t)(row0 + r1) * d.Kreal + (kk) + ko0; \
                fa##S[2] = *(const float4*)p1_;                                \
                fa##S[3] = *(const float4*)(p1_ + 4);                          \
            } else {                                                           \
                fa##S[0] = fa##S[1] = fa##S[2] = fa##S[3] =                    \
                    (float4){0.f, 0.f, 0.f, 0.f};                              \
            }                                                                  \
        } else {                                                               \
            ba##S[0] = *(const uint4*)(d.Ab + (size_t)(row0 + r0) * d.K + (kk) + ko0); \
            ba##S[1] = *(const uint4*)(d.Ab + (size_t)(row0 + r1) * d.K + (kk) + ko0); \
        }                                                                      \
        bb##S[0] = *(const uint4*)(d.W + (size_t)(col0 + r0) * d.K + (kk) + ko0); \
        bb##S[1] = *(const uint4*)(d.W + (size_t)(col0 + r1) * d.K + (kk) + ko0); \
    } while (0)

#define PACKU4(lo, hi)                                                         \
    (uint4){ f2bf((lo).x) | ((unsigned)f2bf((lo).y) << 16),                    \
             f2bf((lo).z) | ((unsigned)f2bf((lo).w) << 16),                    \
             f2bf((hi).x) | ((unsigned)f2bf((hi).y) << 16),                    \
             f2bf((hi).z) | ((unsigned)f2bf((hi).w) << 16) }

#define STORE(S, buf)                                                          \
    do {                                                                       \
        if (afp) {                                                             \
            *(uint4*)&As[buf][tid * 8]        = PACKU4(fa##S[0], fa##S[1]);    \
            *(uint4*)&As[buf][tid * 8 + 2048] = PACKU4(fa##S[2], fa##S[3]);    \
        } else {                                                               \
            *(uint4*)&As[buf][tid * 8]        = ba##S[0];                      \
            *(uint4*)&As[buf][tid * 8 + 2048] = ba##S[1];                      \
        }                                                                      \
        *(uint4*)&Bs[buf][tid * 8]        = bb##S[0];                          \
        *(uint4*)&Bs[buf][tid * 8 + 2048] = bb##S[1];                          \
    } while (0)

#define MFMA(buf)                                                              \
    do {                                                                       \
        short8 a_[4], b_[4];                                                   \
        _Pragma("unroll")                                                      \
        for (int i = 0; i < 4; ++i)                                            \
            a_[i] = *(const short8*)&As[buf][(wr + i * 16 + ln) * 32 + qd * 8];\
        _Pragma("unroll")                                                      \
        for (int j = 0; j < 4; ++j)                                            \
            b_[j] = *(const short8*)&Bs[buf][(wc + j * 16 + ln) * 32 + qd * 8];\
        _Pragma("unroll")                                                      \
        for (int i = 0; i < 4; ++i)                                            \
            _Pragma("unroll")                                                  \
            for (int j = 0; j < 4; ++j)                                        \
                acc[i][j] = __builtin_amdgcn_mfma_f32_16x16x32_bf16(           \
                                a_[i], b_[j], acc[i][j], 0, 0, 0);             \
    } while (0)

    floatx4 acc[4][4];
    #pragma unroll
    for (int i = 0; i < 4; ++i)
        #pragma unroll
        for (int j = 0; j < 4; ++j) acc[i][j] = (floatx4){0.f, 0.f, 0.f, 0.f};

    // prologue: tile0 -> set0, tile1 -> set1; set0 -> LDS buf0
    LOAD(0, 0);
    if (T > 1) LOAD(1, 32);
    STORE(0, 0);
    __syncthreads();

    for (int it = 0; it < T; it += 2) {
        // half A: compute tile it (buf0); prefetch tile it+2 -> set0
        if (it + 2 < T) LOAD(0, (it + 2) * 32);
        MFMA(0);
        if (it + 1 < T) STORE(1, 1);
        __syncthreads();
        // half B: compute tile it+1 (buf1); prefetch tile it+3 -> set1
        if (it + 1 < T) {
            if (it + 3 < T) LOAD(1, (it + 3) * 32);
            MFMA(1);
            if (it + 2 < T) STORE(0, 0);
            __syncthreads();
        }
    }
#undef LOAD
#undef PACKU4
#undef STORE
#undef MFMA

    // epilogue: C/D layout col = lane&15, row = quad*4 + reg
    #pragma unroll
    for (int j = 0; j < 4; ++j) {
        const int col = col0 + wc + j * 16 + ln;
        float add = d.bias ? d.bias[col] : 0.f;
        float scale = 1.f, shift = 0.f;
        if (d.fuse) {
            scale = d.g[col] * rsqrtf(d.v[col] + 1e-5f);
            shift = d.b[col] - d.m[col] * scale;
        }
        #pragma unroll
        for (int i = 0; i < 4; ++i) {
            #pragma unroll
            for (int r = 0; r < 4; ++r) {
                const int row = row0 + wr + i * 16 + qd * 4 + r;
                float vv = acc[i][j][r] + add;
                if (d.fuse) vv = fmaxf(vv * scale + shift, 0.f);
                if (d.Cf) d.Cf[(size_t)row * d.N + col] = vv;
                if (d.Cb) d.Cb[(size_t)row * d.N + col] = f2bf(vv);
            }
        }
    }
}

// ---------------------------------------------------------------------------
// One-shot weight conversion fp32 -> bf16 (fc weight zero-padded 688->704)
// ---------------------------------------------------------------------------
struct WSeg { const float* src; unsigned short* dst; int Kreal; int Kp; };
struct WArgs { WSeg s[7]; int off[8]; };

__global__ __launch_bounds__(256)
void cvt_weights(WArgs wa)
{
    int i = blockIdx.x * 256 + threadIdx.x;
    if (i >= wa.off[7]) return;
    int s = 0;
    #pragma unroll
    for (int j = 1; j < 7; ++j) if (i >= wa.off[j]) s = j;
    const WSeg sg = wa.s[s];
    const int li = i - wa.off[s];
    const int r = li / sg.Kp, c = li - r * sg.Kp;
    sg.dst[li] = (c < sg.Kreal) ? f2bf(sg.src[(size_t)r * sg.Kreal + c])
                                : (unsigned short)0;
}

// ---------------------------------------------------------------------------
// Fused attention per batch row. MLP outputs bf16.
// ---------------------------------------------------------------------------
__global__ __launch_bounds__(256)
void attn_kernel(const unsigned short* __restrict__ obj,
                 const float* __restrict__ bbox,
                 const float* __restrict__ word,
                 const unsigned short* __restrict__ sen,
                 const unsigned short* __restrict__ bod,
                 const float* __restrict__ Wc1, const float* __restrict__ Wc2,
                 const float* __restrict__ Wsa,
                 float* __restrict__ xsum_out)
{
    const int b = blockIdx.x;
    const int tid = threadIdx.x;
    const int wave = tid >> 6;
    const int lane = tid & 63;

    __shared__ float xs[10][688];
    __shared__ float s0[688], s1[688];
    __shared__ float avec[10], mvec[10], att[10];
    __shared__ float cw[14], c1[50], c2[50];

    if (tid < 14) cw[tid] = Wsa[tid];
    if (tid < 50) { c1[tid] = Wc1[tid]; c2[tid] = Wc2[tid]; }

    for (int n = 0; n < 10; ++n) {
        const unsigned short* o = obj + ((size_t)b * 10 + n) * 128;
        const float* bx = bbox + ((size_t)b * 10 + n) * 4;
        const float* w  = word + ((size_t)b * 10 + n) * 300;
        const unsigned short* s = sen + ((size_t)b * 10 + n) * 128;
        const unsigned short* bo = bod + (size_t)b * 128;
        for (int c = tid; c < 688; c += 256) {
            float v;
            if      (c < 128) v = bf2f(o[c]);
            else if (c < 132) v = bx[c - 128];
            else if (c < 432) v = w[c - 132];
            else if (c < 560) v = bf2f(s[c - 432]);
            else              v = bf2f(bo[c - 560]);
            xs[n][c] = v;
        }
    }
    __syncthreads();

    for (int n = wave; n < 10; n += 4) {
        float sm = 0.f, mx = -INFINITY;
        for (int c = lane; c < 688; c += 64) {
            float v = xs[n][c];
            sm += v; mx = fmaxf(mx, v);
        }
        #pragma unroll
        for (int off = 32; off > 0; off >>= 1) {
            sm += __shfl_down(sm, off);
            mx = fmaxf(mx, __shfl_down(mx, off));
        }
        if (lane == 0) { avec[n] = sm * (1.f / 688.f); mvec[n] = mx; }
    }
    __syncthreads();

    if (tid == 0) {
        float ha[5], hm[5];
        #pragma unroll
        for (int i = 0; i < 5; ++i) {
            float sa_ = 0.f, sm_ = 0.f;
            #pragma unroll
            for (int j = 0; j < 10; ++j) {
                sa_ += c1[i * 10 + j] * avec[j];
                sm_ += c1[i * 10 + j] * mvec[j];
            }
            ha[i] = fmaxf(sa_, 0.f);
            hm[i] = fmaxf(sm_, 0.f);
        }
        #pragma unroll
        for (int j = 0; j < 10; ++j) {
            float v = 0.f;
            #pragma unroll
            for (int i = 0; i < 5; ++i) v += c2[j * 5 + i] * (ha[i] + hm[i]);
            att[j] = 1.f / (1.f + expf(-v));
        }
    }
    __syncthreads();

    for (int c = tid; c < 688; c += 256) {
        float sm = 0.f, mx = -INFINITY;
        #pragma unroll
        for (int n = 0; n < 10; ++n) {
            float v = xs[n][c] * att[n];
            xs[n][c] = v;
            sm += v; mx = fmaxf(mx, v);
        }
        s0[c] = sm * 0.1f;
        s1[c] = mx;
    }
    __syncthreads();

    for (int c = tid; c < 688; c += 256) {
        float sa = 0.f;
        #pragma unroll
        for (int j = 0; j < 7; ++j) {
            int cc = c + j - 3;
            if (cc >= 0 && cc < 688)
                sa += cw[j] * s0[cc] + cw[7 + j] * s1[cc];
        }
        float sig = 1.f / (1.f + expf(-sa));
        float sm = 0.f;
        #pragma unroll
        for (int n = 0; n < 10; ++n) sm += xs[n][c];
        xsum_out[(size_t)b * 688 + c] = sm * sig;
    }
}

// ---------------------------------------------------------------------------
extern "C" void kernel_launch(void* const* d_in, const int* in_sizes, int n_in,
                              void* d_out, int out_size, void* d_ws, size_t ws_size,
                              hipStream_t stream)
{
    const float* f_obj = (const float*)d_in[0];
    const float* bbox  = (const float*)d_in[1];
    const float* word  = (const float*)d_in[2];
    const float* sent  = (const float*)d_in[3];
    const float* body  = (const float*)d_in[4];
    const float* W1_o  = (const float*)d_in[5];
    const float* g_o = (const float*)d_in[6],  *b_o = (const float*)d_in[7];
    const float* m_o = (const float*)d_in[8],  *v_o = (const float*)d_in[9];
    const float* W2_o  = (const float*)d_in[10];
    const float* W1_s  = (const float*)d_in[11];
    const float* g_s = (const float*)d_in[12], *b_s = (const float*)d_in[13];
    const float* m_s = (const float*)d_in[14], *v_s = (const float*)d_in[15];
    const float* W2_s  = (const float*)d_in[16];
    const float* W1_b  = (const float*)d_in[17];
    const float* g_b = (const float*)d_in[18], *b_b = (const float*)d_in[19];
    const float* m_b = (const float*)d_in[20], *v_b = (const float*)d_in[21];
    const float* W2_b  = (const float*)d_in[22];
    const float* Wc1 = (const float*)d_in[23];
    const float* Wc2 = (const float*)d_in[24];
    const float* Wsa = (const float*)d_in[25];
    const float* Wf  = (const float*)d_in[26];
    const float* bf  = (const float*)d_in[27];
    const float* g_f = (const float*)d_in[28], *b_f = (const float*)d_in[29];
    const float* m_f = (const float*)d_in[30], *v_f = (const float*)d_in[31];
    float* out = (float*)d_out;

    // ---- workspace carve; total ~28.0 MB ----
    char* p = (char*)d_ws;
    unsigned short* w1s = (unsigned short*)p; p += 4194304;   // 512*4096
    unsigned short* w2s = (unsigned short*)p; p += 131072;    // 128*512
    unsigned short* w1o = (unsigned short*)p; p += 262144;    // 128*1024
    unsigned short* w2o = (unsigned short*)p; p += 32768;     // 128*128
    unsigned short* w1b = (unsigned short*)p; p += 1048576;   // 256*2048
    unsigned short* w2b = (unsigned short*)p; p += 65536;     // 128*256
    unsigned short* wfp = (unsigned short*)p; p += 360448;    // 256*704 padded
    unsigned short* h_s = (unsigned short*)p; p += 10485760;  // 10240*512
    unsigned short* h_o = (unsigned short*)p; p += 2621440;   // 10240*128
    unsigned short* h_b = (unsigned short*)p; p += 524288;    // 1024*256
    unsigned short* sen_b = (unsigned short*)p; p += 2621440; // 10240*128
    unsigned short* obj_b = (unsigned short*)p; p += 2621440; // 10240*128
    unsigned short* bod_b = (unsigned short*)p; p += 262144;  // 1024*128
    float* xsum_f = (float*)p; p += 2818048;                  // 1024*688
    if ((size_t)(p - (char*)d_ws) > ws_size) return;

    // ---- 1) weights -> bf16 ----
    WArgs wa;
    wa.s[0] = { W1_s, w1s, 4096, 4096 };
    wa.s[1] = { W2_s, w2s,  512,  512 };
    wa.s[2] = { W1_o, w1o, 1024, 1024 };
    wa.s[3] = { W2_o, w2o,  128,  128 };
    wa.s[4] = { W1_b, w1b, 2048, 2048 };
    wa.s[5] = { W2_b, w2b,  256,  256 };
    wa.s[6] = { Wf,   wfp,  688,  704 };
    const int wn[7] = { 512*4096, 128*512, 128*1024, 128*128, 256*2048, 128*256, 256*704 };
    wa.off[0] = 0;
    for (int i = 0; i < 7; ++i) wa.off[i + 1] = wa.off[i] + wn[i];
    cvt_weights<<<(wa.off[7] + 255) / 256, 256, 0, stream>>>(wa);

    // ---- 2) stage-1 grouped GEMM (fp32 A fused-convert; BN+ReLU; bf16 out) ----
    {
        GArgs ga; ga.n = 3;
        ga.g[0] = { sent,  nullptr, w1s, nullptr, h_s, nullptr, g_s, b_s, m_s, v_s,
                    10240, 512, 4096, 4096, 1, 4, 0, 1 };      // swizzled
        ga.g[1] = { f_obj, nullptr, w1o, nullptr, h_o, nullptr, g_o, b_o, m_o, v_o,
                    10240, 128, 1024, 1024, 1, 1, 320, 0 };
        ga.g[2] = { body,  nullptr, w1b, nullptr, h_b, nullptr, g_b, b_b, m_b, v_b,
                    1024, 256, 2048, 2048, 1, 2, 400, 0 };
        gemm_pipe<<<416, 256, 0, stream>>>(ga);
    }

    // ---- 3) stage-2 grouped GEMM (bf16 A; bf16 out) ----
    {
        GArgs ga; ga.n = 3;
        ga.g[0] = { nullptr, h_s, w2s, nullptr, sen_b, nullptr, nullptr, nullptr, nullptr, nullptr,
                    10240, 128, 512, 512, 0, 1, 0, 0 };
        ga.g[1] = { nullptr, h_o, w2o, nullptr, obj_b, nullptr, nullptr, nullptr, nullptr, nullptr,
                    10240, 128, 128, 128, 0, 1, 80, 0 };
        ga.g[2] = { nullptr, h_b, w2b, nullptr, bod_b, nullptr, nullptr, nullptr, nullptr, nullptr,
                    1024, 128, 256, 256, 0, 1, 160, 0 };
        gemm_pipe<<<168, 256, 0, stream>>>(ga);
    }

    // ---- 4) fused attention + sum over N ----
    attn_kernel<<<1024, 256, 0, stream>>>(obj_b, bbox, word, sen_b, bod_b,
                                          Wc1, Wc2, Wsa, xsum_f);

    // ---- 5) fc1 (+bias, BN, ReLU), K 688 zero-padded to 704 in staging ----
    {
        GArgs ga; ga.n = 1;
        ga.g[0] = { xsum_f, nullptr, wfp, out, nullptr, bf, g_f, b_f, m_f, v_f,
                    1024, 256, 704, 688, 1, 2, 0, 0 };
        gemm_pipe<<<16, 256, 0, stream>>>(ga);
    }
}

// Round 6
// 569.893 us; speedup vs baseline: 1.7681x; 1.1259x over previous
//
#include <hip/hip_runtime.h>
#include <hip/hip_bf16.h>
#include <math.h>

typedef __attribute__((ext_vector_type(8))) short short8;   // 8 x bf16 (4 VGPRs)
typedef __attribute__((ext_vector_type(4))) float floatx4;  // MFMA C/D frag

static __device__ __forceinline__ unsigned short f2bf(float f) {
    unsigned int u = __float_as_uint(f);
    unsigned int r = (u + 0x7fffu + ((u >> 16) & 1u)) >> 16;   // RNE
    return (unsigned short)r;
}
static __device__ __forceinline__ float bf2f(unsigned short h) {
    return __uint_as_float(((unsigned int)h) << 16);
}

// ---------------------------------------------------------------------------
// Grouped bf16 MFMA GEMM.  C[M,N] = A[M,K] @ W[N,K]^T
// Tile 128x64 (BK=32) -> 2x the blocks of 128x128: sentiment GEMM gets 640
// blocks = 2.5-3.25 blocks/CU, so co-resident blocks hide memory latency
// (round-5 lesson: 320 blocks = 1.25/CU cannot hide ~900cyc HBM latency).
// Staging is register-based with distance-1 prefetch: loads for tile k+1
// issue after the first barrier of tile k and are consumed by ds_write a
// full iteration later. Single LDS buffer (12 KB/block).
// A fp32 (converted in regs; zero-pad via Kreal, %8==0) or bf16. W bf16.
// 4 waves; wave w computes rows w*32..w*32+31 x all 64 cols (2x4 MFMAs).
// ---------------------------------------------------------------------------
struct GDesc {
    const float*          Af;    // fp32 A (or null)
    const unsigned short* Ab;    // bf16 A (or null)
    const unsigned short* W;     // bf16 W, row stride K
    float*          Cf;          // fp32 out (or null)
    unsigned short* Cb;          // bf16 out (or null)
    const float *bias, *g, *b, *m, *v;
    int M, N, K;                 // K mult of 32 (W stride, LDS tile)
    int Kreal;                   // A row stride / true K
    int fuse;                    // BN+ReLU epilogue
    int nbx;                     // N/64
    int block0;                  // first flat block of group
};
struct GArgs { GDesc g[3]; int n; };

__global__ __launch_bounds__(256)
void gemm_g64(GArgs ga)
{
    __shared__ unsigned short As[128 * 32];   // 8 KB
    __shared__ unsigned short Ws[64 * 32];    // 4 KB

    const int bid = blockIdx.x;
    int gi = 0;
    #pragma unroll
    for (int i = 1; i < 3; ++i)
        if (i < ga.n && bid >= ga.g[i].block0) gi = i;
    const GDesc d = ga.g[gi];
    const int local = bid - d.block0;
    const int bx = local % d.nbx;
    const int by = local / d.nbx;
    const int row0 = by * 128;
    const int col0 = bx * 64;

    const int tid  = threadIdx.x;
    const int wave = tid >> 6;
    const int lane = tid & 63;
    const int qd   = lane >> 4;
    const int ln   = lane & 15;
    const int wr   = wave * 32;          // wave's 32-row strip

    // staging: A chunk c (16B) -> row c>>2, koff (c&3)*8 ; thread owns c=tid, tid+256
    // W chunk c=tid -> row tid>>2, koff (tid&3)*8
    const int r0  = tid >> 2;            // 0..63
    const int ko0 = (tid & 3) * 8;
    const int r1  = r0 + 64;

    const bool afp = (d.Af != nullptr);
    const int T = d.K >> 5;

    float4 fa[4];    // fp32 A stage (rows r0, r1; 8 floats each)
    uint4  ab[2];    // bf16 A stage
    uint4  wb;       // W stage

#define LOADA(kk)                                                              \
    do {                                                                       \
        if (afp) {                                                             \
            if ((kk) + ko0 < d.Kreal) {                                        \
                const float* p0_ = d.Af + (size_t)(row0 + r0) * d.Kreal + (kk) + ko0; \
                fa[0] = *(const float4*)p0_;                                   \
                fa[1] = *(const float4*)(p0_ + 4);                             \
                const float* p1_ = d.Af + (size_t)(row0 + r1) * d.Kreal + (kk) + ko0; \
                fa[2] = *(const float4*)p1_;                                   \
                fa[3] = *(const float4*)(p1_ + 4);                             \
            } else {                                                           \
                fa[0] = fa[1] = fa[2] = fa[3] = (float4){0.f, 0.f, 0.f, 0.f};  \
            }                                                                  \
        } else {                                                               \
            ab[0] = *(const uint4*)(d.Ab + (size_t)(row0 + r0) * d.K + (kk) + ko0); \
            ab[1] = *(const uint4*)(d.Ab + (size_t)(row0 + r1) * d.K + (kk) + ko0); \
        }                                                                      \
        wb = *(const uint4*)(d.W + (size_t)(col0 + r0) * d.K + (kk) + ko0);    \
    } while (0)

#define PACKU4(lo, hi)                                                         \
    (uint4){ f2bf((lo).x) | ((unsigned)f2bf((lo).y) << 16),                    \
             f2bf((lo).z) | ((unsigned)f2bf((lo).w) << 16),                    \
             f2bf((hi).x) | ((unsigned)f2bf((hi).y) << 16),                    \
             f2bf((hi).z) | ((unsigned)f2bf((hi).w) << 16) }

#define STORE()                                                                \
    do {                                                                       \
        if (afp) {                                                             \
            *(uint4*)&As[tid * 8]        = PACKU4(fa[0], fa[1]);               \
            *(uint4*)&As[tid * 8 + 2048] = PACKU4(fa[2], fa[3]);               \
        } else {                                                               \
            *(uint4*)&As[tid * 8]        = ab[0];                              \
            *(uint4*)&As[tid * 8 + 2048] = ab[1];                              \
        }                                                                      \
        *(uint4*)&Ws[tid * 8] = wb;                                            \
    } while (0)

    floatx4 acc[2][4];
    #pragma unroll
    for (int i = 0; i < 2; ++i)
        #pragma unroll
        for (int j = 0; j < 4; ++j) acc[i][j] = (floatx4){0.f, 0.f, 0.f, 0.f};

    LOADA(0);
    for (int it = 0; it < T; ++it) {
        STORE();                     // regs from iter it-1's load (dist-1)
        __syncthreads();
        if (it + 1 < T) LOADA((it + 1) * 32);   // in flight across MFMA+barrier

        short8 a_[2], b_[4];
        #pragma unroll
        for (int i = 0; i < 2; ++i)
            a_[i] = *(const short8*)&As[(wr + i * 16 + ln) * 32 + qd * 8];
        #pragma unroll
        for (int j = 0; j < 4; ++j)
            b_[j] = *(const short8*)&Ws[(j * 16 + ln) * 32 + qd * 8];
        #pragma unroll
        for (int i = 0; i < 2; ++i)
            #pragma unroll
            for (int j = 0; j < 4; ++j)
                acc[i][j] = __builtin_amdgcn_mfma_f32_16x16x32_bf16(
                                a_[i], b_[j], acc[i][j], 0, 0, 0);
        __syncthreads();
    }
#undef LOADA
#undef PACKU4
#undef STORE

    // epilogue: C/D layout col = lane&15, row = quad*4 + reg
    #pragma unroll
    for (int j = 0; j < 4; ++j) {
        const int col = col0 + j * 16 + ln;
        float add = d.bias ? d.bias[col] : 0.f;
        float scale = 1.f, shift = 0.f;
        if (d.fuse) {
            scale = d.g[col] * rsqrtf(d.v[col] + 1e-5f);
            shift = d.b[col] - d.m[col] * scale;
        }
        #pragma unroll
        for (int i = 0; i < 2; ++i) {
            #pragma unroll
            for (int r = 0; r < 4; ++r) {
                const int row = row0 + wr + i * 16 + qd * 4 + r;
                float vv = acc[i][j][r] + add;
                if (d.fuse) vv = fmaxf(vv * scale + shift, 0.f);
                if (d.Cf) d.Cf[(size_t)row * d.N + col] = vv;
                if (d.Cb) d.Cb[(size_t)row * d.N + col] = f2bf(vv);
            }
        }
    }
}

// ---------------------------------------------------------------------------
// One-shot weight conversion fp32 -> bf16 (fc weight zero-padded 688->704)
// ---------------------------------------------------------------------------
struct WSeg { const float* src; unsigned short* dst; int Kreal; int Kp; };
struct WArgs { WSeg s[7]; int off[8]; };

__global__ __launch_bounds__(256)
void cvt_weights(WArgs wa)
{
    int i = blockIdx.x * 256 + threadIdx.x;
    if (i >= wa.off[7]) return;
    int s = 0;
    #pragma unroll
    for (int j = 1; j < 7; ++j) if (i >= wa.off[j]) s = j;
    const WSeg sg = wa.s[s];
    const int li = i - wa.off[s];
    const int r = li / sg.Kp, c = li - r * sg.Kp;
    sg.dst[li] = (c < sg.Kreal) ? f2bf(sg.src[(size_t)r * sg.Kreal + c])
                                : (unsigned short)0;
}

// ---------------------------------------------------------------------------
// Fused attention per batch row. MLP outputs bf16.
// ---------------------------------------------------------------------------
__global__ __launch_bounds__(256)
void attn_kernel(const unsigned short* __restrict__ obj,
                 const float* __restrict__ bbox,
                 const float* __restrict__ word,
                 const unsigned short* __restrict__ sen,
                 const unsigned short* __restrict__ bod,
                 const float* __restrict__ Wc1, const float* __restrict__ Wc2,
                 const float* __restrict__ Wsa,
                 float* __restrict__ xsum_out)
{
    const int b = blockIdx.x;
    const int tid = threadIdx.x;
    const int wave = tid >> 6;
    const int lane = tid & 63;

    __shared__ float xs[10][688];
    __shared__ float s0[688], s1[688];
    __shared__ float avec[10], mvec[10], att[10];
    __shared__ float cw[14], c1[50], c2[50];

    if (tid < 14) cw[tid] = Wsa[tid];
    if (tid < 50) { c1[tid] = Wc1[tid]; c2[tid] = Wc2[tid]; }

    for (int n = 0; n < 10; ++n) {
        const unsigned short* o = obj + ((size_t)b * 10 + n) * 128;
        const float* bx = bbox + ((size_t)b * 10 + n) * 4;
        const float* w  = word + ((size_t)b * 10 + n) * 300;
        const unsigned short* s = sen + ((size_t)b * 10 + n) * 128;
        const unsigned short* bo = bod + (size_t)b * 128;
        for (int c = tid; c < 688; c += 256) {
            float v;
            if      (c < 128) v = bf2f(o[c]);
            else if (c < 132) v = bx[c - 128];
            else if (c < 432) v = w[c - 132];
            else if (c < 560) v = bf2f(s[c - 432]);
            else              v = bf2f(bo[c - 560]);
            xs[n][c] = v;
        }
    }
    __syncthreads();

    for (int n = wave; n < 10; n += 4) {
        float sm = 0.f, mx = -INFINITY;
        for (int c = lane; c < 688; c += 64) {
            float v = xs[n][c];
            sm += v; mx = fmaxf(mx, v);
        }
        #pragma unroll
        for (int off = 32; off > 0; off >>= 1) {
            sm += __shfl_down(sm, off);
            mx = fmaxf(mx, __shfl_down(mx, off));
        }
        if (lane == 0) { avec[n] = sm * (1.f / 688.f); mvec[n] = mx; }
    }
    __syncthreads();

    if (tid == 0) {
        float ha[5], hm[5];
        #pragma unroll
        for (int i = 0; i < 5; ++i) {
            float sa_ = 0.f, sm_ = 0.f;
            #pragma unroll
            for (int j = 0; j < 10; ++j) {
                sa_ += c1[i * 10 + j] * avec[j];
                sm_ += c1[i * 10 + j] * mvec[j];
            }
            ha[i] = fmaxf(sa_, 0.f);
            hm[i] = fmaxf(sm_, 0.f);
        }
        #pragma unroll
        for (int j = 0; j < 10; ++j) {
            float v = 0.f;
            #pragma unroll
            for (int i = 0; i < 5; ++i) v += c2[j * 5 + i] * (ha[i] + hm[i]);
            att[j] = 1.f / (1.f + expf(-v));
        }
    }
    __syncthreads();

    for (int c = tid; c < 688; c += 256) {
        float sm = 0.f, mx = -INFINITY;
        #pragma unroll
        for (int n = 0; n < 10; ++n) {
            float v = xs[n][c] * att[n];
            xs[n][c] = v;
            sm += v; mx = fmaxf(mx, v);
        }
        s0[c] = sm * 0.1f;
        s1[c] = mx;
    }
    __syncthreads();

    for (int c = tid; c < 688; c += 256) {
        float sa = 0.f;
        #pragma unroll
        for (int j = 0; j < 7; ++j) {
            int cc = c + j - 3;
            if (cc >= 0 && cc < 688)
                sa += cw[j] * s0[cc] + cw[7 + j] * s1[cc];
        }
        float sig = 1.f / (1.f + expf(-sa));
        float sm = 0.f;
        #pragma unroll
        for (int n = 0; n < 10; ++n) sm += xs[n][c];
        xsum_out[(size_t)b * 688 + c] = sm * sig;
    }
}

// ---------------------------------------------------------------------------
extern "C" void kernel_launch(void* const* d_in, const int* in_sizes, int n_in,
                              void* d_out, int out_size, void* d_ws, size_t ws_size,
                              hipStream_t stream)
{
    const float* f_obj = (const float*)d_in[0];
    const float* bbox  = (const float*)d_in[1];
    const float* word  = (const float*)d_in[2];
    const float* sent  = (const float*)d_in[3];
    const float* body  = (const float*)d_in[4];
    const float* W1_o  = (const float*)d_in[5];
    const float* g_o = (const float*)d_in[6],  *b_o = (const float*)d_in[7];
    const float* m_o = (const float*)d_in[8],  *v_o = (const float*)d_in[9];
    const float* W2_o  = (const float*)d_in[10];
    const float* W1_s  = (const float*)d_in[11];
    const float* g_s = (const float*)d_in[12], *b_s = (const float*)d_in[13];
    const float* m_s = (const float*)d_in[14], *v_s = (const float*)d_in[15];
    const float* W2_s  = (const float*)d_in[16];
    const float* W1_b  = (const float*)d_in[17];
    const float* g_b = (const float*)d_in[18], *b_b = (const float*)d_in[19];
    const float* m_b = (const float*)d_in[20], *v_b = (const float*)d_in[21];
    const float* W2_b  = (const float*)d_in[22];
    const float* Wc1 = (const float*)d_in[23];
    const float* Wc2 = (const float*)d_in[24];
    const float* Wsa = (const float*)d_in[25];
    const float* Wf  = (const float*)d_in[26];
    const float* bf  = (const float*)d_in[27];
    const float* g_f = (const float*)d_in[28], *b_f = (const float*)d_in[29];
    const float* m_f = (const float*)d_in[30], *v_f = (const float*)d_in[31];
    float* out = (float*)d_out;

    // ---- workspace carve; total ~28.0 MB ----
    char* p = (char*)d_ws;
    unsigned short* w1s = (unsigned short*)p; p += 4194304;   // 512*4096
    unsigned short* w2s = (unsigned short*)p; p += 131072;    // 128*512
    unsigned short* w1o = (unsigned short*)p; p += 262144;    // 128*1024
    unsigned short* w2o = (unsigned short*)p; p += 32768;     // 128*128
    unsigned short* w1b = (unsigned short*)p; p += 1048576;   // 256*2048
    unsigned short* w2b = (unsigned short*)p; p += 65536;     // 128*256
    unsigned short* wfp = (unsigned short*)p; p += 360448;    // 256*704 padded
    unsigned short* h_s = (unsigned short*)p; p += 10485760;  // 10240*512
    unsigned short* h_o = (unsigned short*)p; p += 2621440;   // 10240*128
    unsigned short* h_b = (unsigned short*)p; p += 524288;    // 1024*256
    unsigned short* sen_b = (unsigned short*)p; p += 2621440; // 10240*128
    unsigned short* obj_b = (unsigned short*)p; p += 2621440; // 10240*128
    unsigned short* bod_b = (unsigned short*)p; p += 262144;  // 1024*128
    float* xsum_f = (float*)p; p += 2818048;                  // 1024*688
    if ((size_t)(p - (char*)d_ws) > ws_size) return;

    // ---- 1) weights -> bf16 ----
    WArgs wa;
    wa.s[0] = { W1_s, w1s, 4096, 4096 };
    wa.s[1] = { W2_s, w2s,  512,  512 };
    wa.s[2] = { W1_o, w1o, 1024, 1024 };
    wa.s[3] = { W2_o, w2o,  128,  128 };
    wa.s[4] = { W1_b, w1b, 2048, 2048 };
    wa.s[5] = { W2_b, w2b,  256,  256 };
    wa.s[6] = { Wf,   wfp,  688,  704 };
    const int wn[7] = { 512*4096, 128*512, 128*1024, 128*128, 256*2048, 128*256, 256*704 };
    wa.off[0] = 0;
    for (int i = 0; i < 7; ++i) wa.off[i + 1] = wa.off[i] + wn[i];
    cvt_weights<<<(wa.off[7] + 255) / 256, 256, 0, stream>>>(wa);

    // ---- 2) stage-1 grouped GEMM (fp32 A fused-convert; BN+ReLU; bf16 out) ----
    {
        GArgs ga; ga.n = 3;
        ga.g[0] = { sent,  nullptr, w1s, nullptr, h_s, nullptr, g_s, b_s, m_s, v_s,
                    10240, 512, 4096, 4096, 1, 8, 0 };     // 640 blocks
        ga.g[1] = { f_obj, nullptr, w1o, nullptr, h_o, nullptr, g_o, b_o, m_o, v_o,
                    10240, 128, 1024, 1024, 1, 2, 640 };   // 160 blocks
        ga.g[2] = { body,  nullptr, w1b, nullptr, h_b, nullptr, g_b, b_b, m_b, v_b,
                    1024, 256, 2048, 2048, 1, 4, 800 };    // 32 blocks
        gemm_g64<<<832, 256, 0, stream>>>(ga);
    }

    // ---- 3) stage-2 grouped GEMM (bf16 A; bf16 out) ----
    {
        GArgs ga; ga.n = 3;
        ga.g[0] = { nullptr, h_s, w2s, nullptr, sen_b, nullptr, nullptr, nullptr, nullptr, nullptr,
                    10240, 128, 512, 512, 0, 2, 0 };       // 160 blocks
        ga.g[1] = { nullptr, h_o, w2o, nullptr, obj_b, nullptr, nullptr, nullptr, nullptr, nullptr,
                    10240, 128, 128, 128, 0, 2, 160 };     // 160 blocks
        ga.g[2] = { nullptr, h_b, w2b, nullptr, bod_b, nullptr, nullptr, nullptr, nullptr, nullptr,
                    1024, 128, 256, 256, 0, 2, 320 };      // 16 blocks
        gemm_g64<<<336, 256, 0, stream>>>(ga);
    }

    // ---- 4) fused attention + sum over N ----
    attn_kernel<<<1024, 256, 0, stream>>>(obj_b, bbox, word, sen_b, bod_b,
                                          Wc1, Wc2, Wsa, xsum_f);

    // ---- 5) fc1 (+bias, BN, ReLU), K 688 zero-padded to 704 in staging ----
    {
        GArgs ga; ga.n = 1;
        ga.g[0] = { xsum_f, nullptr, wfp, out, nullptr, bf, g_f, b_f, m_f, v_f,
                    1024, 256, 704, 688, 1, 4, 0 };        // 32 blocks
        gemm_g64<<<32, 256, 0, stream>>>(ga);
    }
}